// Round 1
// 620.867 us; speedup vs baseline: 1.0149x; 1.0149x over previous
//
#include <hip/hip_runtime.h>

#define EPSILON 0.001f
#define NSUP 601
#define BLOCK_THREADS 256
#define ROWS_PER_WAVE 16
#define F4_PER_WAVE 2404   // 16*601/4 — exact; span starts are 64B aligned (16*601*4 = 601*64)

typedef float v4f __attribute__((ext_vector_type(4)));

__device__ __forceinline__ float readlane_f(float v, int l) {
    return __uint_as_float((unsigned)__builtin_amdgcn_readlane((int)__float_as_uint(v), l));
}

// ---------------------------------------------------------------------------
// R9: FUSED SINGLE-PASS. One wave per 16 consecutive rows (9616 floats ==
// 2404 float4, span start 64B-aligned), same dense coalesced dwordx4 sweep
// as the previous best — but each float4 carries its FINAL value, so there
// is no phase 2, no __threadfence_block (vmcnt drain), and no second-touch
// scatter RMW (each output cache line is written exactly once).
//
// Key structure: unrolled iteration i covers elements [256i, 256i+256) of
// the span — less than one 601-float row — so it overlaps at most 2 rows
// rA/rB whose indices are COMPILE-TIME constants after unroll. The two
// special positions (lower/upper) of those rows are pulled from the
// param-holding lanes with v_readlane (constant lane index -> SGPR), and
// merged into the store value with v_cmp/v_cndmask per element. Extra cost
// ~1100 VALU/SALU ops per thread, fully hidden under the HBM store drain.
//
// Params: every lane computes t/lower/upper/p for row 16w+(lane&15) —
// redundant x4 but divergence-free; lanes 0..15 hold rows 0..15 for the
// readlane fetches.
// Collision (top clamp, lower==upper==600): reference's upper write wins;
// the lower compare is evaluated first but substitutes p_high (pl_store),
// so order-independent. Rows rA != rB have disjoint position sets, so the
// A/B merge order is irrelevant.
//
// Discriminating experiment (see journal): if the previous 2-phase
// structure was the limiter (fence + scatter second-touch), dur_us drops
// to ~515-545. If it ties (~630), the remaining time is mandatory bytes
// (2.52 GB poison + 630 MB output at ~6.25 TB/s) + fixed harness overhead
// -> roofline.
// ---------------------------------------------------------------------------
__global__ __launch_bounds__(BLOCK_THREADS)
void twohot_fused_kernel(const float* __restrict__ x,
                         const float* __restrict__ supports,
                         float* __restrict__ out, int nrows) {
    const int lane = threadIdx.x & 63;
    const int w = blockIdx.x * (BLOCK_THREADS / 64) + (threadIdx.x >> 6);
    const int row0 = w * ROWS_PER_WAVE;
    if (row0 >= nrows) return;

    // --- per-row params, computed by all lanes for row0 + (lane&15) ---
    const int r = lane & 15;
    const float v = x[row0 + r];
    const float s = (v > 0.f) ? 1.f : ((v < 0.f) ? -1.f : 0.f);
    const float t = s * (sqrtf(fabsf(v) + 1.f) - 1.f + EPSILON * v);

    // supports = linspace(-300,300,601), unit spacing:
    // searchsorted(right)-1 == floor(t)+300, clamped.
    int idx = (int)floorf(t) + 300;
    const int lower = idx < 0 ? 0 : (idx > NSUP - 1 ? NSUP - 1 : idx);
    const int upper = (lower + 1 > NSUP - 1) ? NSUP - 1 : lower + 1;

    const float ls = supports[lower];
    const float us = supports[upper];
    const float p_low = (us - t) / (us - ls);       // denom == 1.0 in-range
    const float p_high = 1.f - p_low;
    // value stored at the "lower" position: on collision both positions
    // coincide and the reference's upper write wins -> substitute p_high
    const float pl_store = (lower == upper) ? p_high : p_low;

    // span-relative element positions of this lane's row specials
    const int pos_lo = r * NSUP + lower;
    const int pos_hi = r * NSUP + upper;

    v4f* out4 = (v4f*)out + (long long)w * F4_PER_WAVE;
    const int e_lane = lane * 4;

    #pragma unroll
    for (int i = 0; i < F4_PER_WAVE / 64; ++i) {      // 37 full iterations
        const int eb = i * 256;                        // span element base
        const int rA = eb / NSUP;                      // folds to literal
        const int rB = (eb + 255) / NSUP;              // rA or rA+1 (<=15)
        const int   pLoA = __builtin_amdgcn_readlane(pos_lo, rA);
        const int   pHiA = __builtin_amdgcn_readlane(pos_hi, rA);
        const float vLoA = readlane_f(pl_store, rA);
        const float vHiA = readlane_f(p_high, rA);
        const int   pLoB = __builtin_amdgcn_readlane(pos_lo, rB);
        const int   pHiB = __builtin_amdgcn_readlane(pos_hi, rB);
        const float vLoB = readlane_f(pl_store, rB);
        const float vHiB = readlane_f(p_high, rB);
        const int e0 = eb + e_lane;
        v4f val;
        #pragma unroll
        for (int m = 0; m < 4; ++m) {                  // static indices only
            const int e = e0 + m;
            float c = (e == pLoB) ? vLoB : ((e == pHiB) ? vHiB : 0.f);
            c = (e == pLoA) ? vLoA : ((e == pHiA) ? vHiA : c);
            val[m] = c;
        }
        out4[i * 64 + lane] = val;
    }

    // --- tail: f4 slots 2368..2403 (36 lanes), entirely in row slot 15 ---
    {
        const int   pLo = __builtin_amdgcn_readlane(pos_lo, 15);
        const int   pHi = __builtin_amdgcn_readlane(pos_hi, 15);
        const float vLo = readlane_f(pl_store, 15);
        const float vHi = readlane_f(p_high, 15);
        if (lane < F4_PER_WAVE % 64) {                // 36 lanes
            const int e0 = (F4_PER_WAVE / 64) * 256 + e_lane;
            v4f val;
            #pragma unroll
            for (int m = 0; m < 4; ++m) {
                const int e = e0 + m;
                val[m] = (e == pLo) ? vLo : ((e == pHi) ? vHi : 0.f);
            }
            out4[(F4_PER_WAVE / 64) * 64 + lane] = val;
        }
    }
}

extern "C" void kernel_launch(void* const* d_in, const int* in_sizes, int n_in,
                              void* d_out, int out_size, void* d_ws, size_t ws_size,
                              hipStream_t stream) {
    const float* tv = (const float*)d_in[0];
    const float* supports = (const float*)d_in[1];
    float* out = (float*)d_out;

    const int nrows = in_sizes[0];                               // 262144
    const int nwaves = (nrows + ROWS_PER_WAVE - 1) / ROWS_PER_WAVE;  // 16384
    const int nblocks = (nwaves + 3) / 4;                        // 4096
    twohot_fused_kernel<<<nblocks, BLOCK_THREADS, 0, stream>>>(tv, supports, out, nrows);
}